// Round 5
// baseline (458.449 us; speedup 1.0000x reference)
//
#include <hip/hip_runtime.h>

typedef unsigned int u32;
typedef unsigned short u16;
typedef float f32x4 __attribute__((ext_vector_type(4)));
typedef short s16x8 __attribute__((ext_vector_type(8)));
typedef u32 __attribute__((ext_vector_type(4))) u32x4;

// may_alias views for LDS: the pool is accessed as u16 / u32 / u32x4 in
// different phases.
typedef u16 __attribute__((may_alias)) u16a;
typedef u32 __attribute__((may_alias)) u32a;
typedef u32x4 __attribute__((may_alias)) u32x4a;

// Compile-time-only fence: orders LDS stores vs dependent reads in the
// scheduler without emitting any instruction.
#define CFENCE() asm volatile("" ::: "memory")

constexpr float SCALE = 0.17677669529663687f;  // 32^-0.5

__device__ __forceinline__ u16 f2b(float f) {
  u32 x = __float_as_uint(f);
  return (u16)((x + 0x7fffu + ((x >> 16) & 1u)) >> 16);  // RNE-ish
}
__device__ __forceinline__ float b2f(u16 s) { return __uint_as_float(((u32)s) << 16); }
__device__ __forceinline__ u32 pk2(float lo, float hi) {
  return (u32)f2b(lo) | ((u32)f2b(hi) << 16);
}

union FU8 { s16x8 v; u32 u[4]; u32x4 q; };

// Barrier WITHOUT the vmcnt(0) drain __syncthreads() would emit.
__device__ __forceinline__ void barrier_lds() {
  asm volatile("s_waitcnt lgkmcnt(0)" ::: "memory");
  __builtin_amdgcn_s_barrier();
}

// ws tables (u16 bf16):
//   TK  [h][240][32] at 0      (k_embed, rows>=225 zero)      for QE = Q x TK^T
//   TQ  [h][240][32] at 30720  (q_embed*SCALE)                for KR = K x TQ^T
//   TVt [h][32][256] at 61440  (v_embed^T, pp>=225 zero)      for Aacc x VE
__global__ __launch_bounds__(256) void prep_tabs(const float* __restrict__ rpe,
                                                 u16* __restrict__ tabs) {
  int id = blockIdx.x * 256 + threadIdx.x;
  if (id >= 94208) return;
  float val = 0.f;
  if (id < 61440) {
    int tbl = id / 30720;          // 0 = TK, 1 = TQ
    int r   = id % 30720;
    int h   = r / 7680;
    int rr  = r % 7680;
    int row = rr / 32, c = rr % 32;
    if (row < 225) {
      val = rpe[row * 384 + h * 96 + (tbl == 0 ? 32 : 0) + c];
      if (tbl == 1) val *= SCALE;
    }
  } else {
    int id2 = id - 61440;
    int h  = id2 / 8192;
    int r2 = id2 % 8192;
    int pp = r2 % 256;
    int c  = r2 / 256;
    if (pp < 225) val = rpe[pp * 384 + h * 96 + 64 + c];
  }
  tabs[id] = f2b(val);
}

// 4 waves per (window, head); wave W owns i-strips {2W, 2W+1}.
// qe and pair-sums live in REGISTERS; KRT is per-wave private (each wave's
// i-strip needs only a 30-wide p-window = 3 TQ tiles), so the flash loop has
// ZERO barriers. Only 2 barriers total:
//   #1 after phase 1 (vt visible before first cross-wave PV read at js=1;
//      placed late so vt global-load latency hides under phase 0b/1 work)
//   #2 after flash (WAR: opv overlays vt)
// LDS pool 15104 u16 = 30208 B -> 4+ blocks/CU:
//   vt   [32][136]            @0                 P0->P2 (V^T, u32-packed)
//   wreg per-wave 2688 u16    @4352 + W*2688 :
//        P1: scWT [144][18]   (QE strip, transposed [p][row])
//        P2: kbufT [48][18]   (KRT window, transposed)
//        P4: aacc [16][168]
//   opv  [32][129]            @0                 P3+ (over dead vt)
__global__ __launch_bounds__(256, 4) void swin_mfma(
    const float* __restrict__ qkv,   // [4,128,128,2,384]
    const u16*   __restrict__ tabs,
    float* __restrict__ out) {       // [4,128,128,2,128]
  __shared__ __align__(16) u16 pool[15104];
  u16a* const vt  = (u16a*)pool;
  u32a* const vt32 = (u32a*)pool;

  const int t = threadIdx.x;
  const int W = t >> 6;
  const int t64 = t & 63;
  const int li = t64 & 15, quad = t64 >> 4;
  u16a* const wreg = (u16a*)(pool + 4352 + W * 2688);
  u32a* const wreg32 = (u32a*)wreg;
  u16a* const opv = (u16a*)pool;

  int blk = blockIdx.x;
  blk = ((blk & 7) << 9) | (blk >> 3);   // XCD-aware swizzle (4096 % 8 == 0)
  const int h = blk & 3;
  const int w = blk >> 2;
  const int b = w >> 8;
  const int nw = w & 255;
  const int wi = nw >> 4, wj = nw & 15;
  const bool wi15 = (wi == 15), wj15 = (wj == 15);

  auto tokoff = [&](int m) -> int {
    int y = (wi * 8 + (m >> 4) + 4) & 127;
    int x = (wj * 8 + ((m >> 1) & 7) + 4) & 127;
    return (((b * 128 + y) * 128 + x) * 2 + (m & 1)) * 384;
  };

  // ---- Phase 0a: V^T staging — pair p = t64 (0..63), 8 channels per wave ----
  {
    int p = t64;
    int ch0 = W * 8;
    int vb = tokoff(2 * p) + 256 + h * 32 + ch0;
    float4 a0 = *(const float4*)(qkv + vb);
    float4 a1 = *(const float4*)(qkv + vb + 4);
    float4 c0 = *(const float4*)(qkv + vb + 384);   // same pixel, n=1
    float4 c1 = *(const float4*)(qkv + vb + 388);
    vt32[(ch0 + 0) * 68 + p] = pk2(a0.x, c0.x);
    vt32[(ch0 + 1) * 68 + p] = pk2(a0.y, c0.y);
    vt32[(ch0 + 2) * 68 + p] = pk2(a0.z, c0.z);
    vt32[(ch0 + 3) * 68 + p] = pk2(a0.w, c0.w);
    vt32[(ch0 + 4) * 68 + p] = pk2(a1.x, c1.x);
    vt32[(ch0 + 5) * 68 + p] = pk2(a1.y, c1.y);
    vt32[(ch0 + 6) * 68 + p] = pk2(a1.z, c1.z);
    vt32[(ch0 + 7) * 68 + p] = pk2(a1.w, c1.w);
  }

  // ---- Phase 0b: Q (scaled by SCALE) and all K fragments ----
  const float QS = SCALE;
  FU8 qf[2];
  #pragma unroll
  for (int g = 0; g < 2; ++g) {
    int base = tokoff((2 * W + g) * 16 + li) + h * 32 + quad * 8;
    float4 a = *(const float4*)(qkv + base);
    float4 c = *(const float4*)(qkv + base + 4);
    qf[g].u[0] = pk2(a.x * QS, a.y * QS);
    qf[g].u[1] = pk2(a.z * QS, a.w * QS);
    qf[g].u[2] = pk2(c.x * QS, c.y * QS);
    qf[g].u[3] = pk2(c.z * QS, c.w * QS);
  }
  FU8 kf[8];
  #pragma unroll
  for (int js = 0; js < 8; ++js) {
    int kb = tokoff(js * 16 + li) + 128 + h * 32 + quad * 8;
    float4 a = *(const float4*)(qkv + kb);
    float4 c = *(const float4*)(qkv + kb + 4);
    kf[js].u[0] = pk2(a.x, a.y); kf[js].u[1] = pk2(a.z, a.w);
    kf[js].u[2] = pk2(c.x, c.y); kf[js].u[3] = pk2(c.z, c.w);
  }

  const f32x4 zf = {0.f, 0.f, 0.f, 0.f};

  // ---- Phase 1: QE strips into scWT (per-wave), gather into REGISTERS ----
  u32 qe[2][8];
  #pragma unroll
  for (int g = 0; g < 2; ++g) {
    int ss = 2 * W + g;
    int t0 = (15 * ss) >> 4;
    CFENCE();   // WAR: previous g's gather reads vs this g's stores
    #pragma unroll
    for (int tt = 0; tt < 9; ++tt) {
      FU8 bf;
      bf.q = *(const u32x4*)(tabs + h * 7680 + ((t0 + tt) * 16 + li) * 32 + quad * 8);
      f32x4 acc = __builtin_amdgcn_mfma_f32_16x16x32_bf16(qf[g].v, bf.v, zf, 0, 0, 0);
      u32 idx = (u32)((tt * 16 + li) * 9 + 2 * quad);   // [p][row] u32 pairs
      wreg32[idx] = pk2(acc[0], acc[1]);
      wreg32[idx + 1] = pk2(acc[2], acc[3]);
    }
    CFENCE();   // RAW: stores above vs u16 gather reads below
    int pbase = (ss + 7) * 15 + (li >> 1) + 7;
    int co = t0 * 16;
    #pragma unroll
    for (int js = 0; js < 8; ++js) {
      int p0 = pbase - 15 * js - 2 * quad;
      u32 lo = wreg[(p0 - co) * 18 + li];
      u32 hi = wreg[(p0 - 1 - co) * 18 + li];
      qe[g][js] = lo | (hi << 16);
    }
  }

  barrier_lds();   // barrier #1: vt visible to all (first cross-wave read: PV js=1)

  // ---- Phase 2: flash over j-strips — NO barriers ----
  f32x4 ot[2][2] = {{zf, zf}, {zf, zf}};
  float lsum[2] = {0.f, 0.f};
  u32 pp[2][8];
  u32 ppk[2][2] = {{0, 0}, {0, 0}};
  const int rx_i = wj15 ? (((li >> 1) < 4) ? 1 : 2) : 0;

  #pragma unroll
  for (int js = 0; js < 8; ++js) {
    // per-wave KRT: 3 tiles covering this wave's 30-wide p-window
    const int pw0 = 15 * (2 * W + 7 - js);
    const int pt0 = pw0 >> 4;
    const int cok = pt0 * 16;
    CFENCE();   // WAR: previous js's kbuf reads vs this js's stores
    #pragma unroll
    for (int k = 0; k < 3; ++k) {
      FU8 bf;
      bf.q = *(const u32x4*)(tabs + 30720 + h * 7680 + ((pt0 + k) * 16 + li) * 32 + quad * 8);
      f32x4 acc = __builtin_amdgcn_mfma_f32_16x16x32_bf16(kf[js].v, bf.v, zf, 0, 0, 0);
      u32 idx = (u32)((k * 16 + li) * 9 + 2 * quad);    // kbufT [p][row]
      wreg32[idx] = pk2(acc[0], acc[1]);
      wreg32[idx + 1] = pk2(acc[2], acc[3]);
    }
    CFENCE();   // RAW: kbuf stores vs u16 reads in the g-loop

    const int ry_j = wi15 ? ((js < 4) ? 1 : 2) : 0;
    u32 cpk[2][2];
    #pragma unroll
    for (int g = 0; g < 2; ++g) {
      const int it = 2 * W + g;
      f32x4 s = __builtin_amdgcn_mfma_f32_16x16x32_bf16(kf[js].v, qf[g].v, zf, 0, 0, 0);
      const int ry_i = wi15 ? ((it < 4) ? 1 : 2) : 0;
      const int pbq = (it + 7) * 15 + (li >> 1) + 7 - 15 * js;
      const float qeL = b2f((u16)qe[g][js]);
      const float qeH = b2f((u16)(qe[g][js] >> 16));
      float e[4];
      #pragma unroll
      for (int reg = 0; reg < 4; ++reg) {
        int jl = quad * 4 + reg;
        int jw = jl >> 1;
        int rx_j = wj15 ? ((jw < 4) ? 1 : 2) : 0;
        float v = s[reg] + b2f(wreg[(pbq - jw - cok) * 18 + jl]) +
                  ((reg < 2) ? qeL : qeH);
        bool open = (ry_i == ry_j) && (rx_i == rx_j) &&
                    !((it == js) && ((li >> 1) == jw) && (li != jl));
        e[reg] = open ? __expf(v) : 0.f;
      }
      float a01 = e[0] + e[1], a23 = e[2] + e[3];
      float cs = a01 + a23;
      cs += __shfl_xor(cs, 16, 64);
      cs += __shfl_xor(cs, 32, 64);
      lsum[g] += cs;
      pp[g][js] = pk2(a01, a23);          // pair-sums, kept in registers
      cpk[g][0] = pk2(e[0], e[1]);
      cpk[g][1] = pk2(e[2], e[3]);
    }

    if (js & 1) {  // PV for the completed 32-j block: P via shuffles
      const int pairbase = (js >> 1) * 32;
      FU8 vf0, vf1;
      vf0.q = *(const u32x4a*)&vt[li * 136 + pairbase + quad * 8];
      vf1.q = *(const u32x4a*)&vt[(16 + li) * 136 + pairbase + quad * 8];
      #pragma unroll
      for (int g = 0; g < 2; ++g) {
        FU8 pf;   // B-frag: k = quad*8+e -> src quad (2*(quad&1)+(w>>1)), word (w&1)
        #pragma unroll
        for (int w2 = 0; w2 < 4; ++w2) {
          int srcLane = (2 * (quad & 1) + (w2 >> 1)) * 16 + li;
          u32 rp = (u32)__shfl((int)ppk[g][w2 & 1], srcLane, 64);
          u32 rc = (u32)__shfl((int)cpk[g][w2 & 1], srcLane, 64);
          pf.u[w2] = (quad < 2) ? rp : rc;
        }
        ot[0][g] = __builtin_amdgcn_mfma_f32_16x16x32_bf16(vf0.v, pf.v, ot[0][g], 0, 0, 0);
        ot[1][g] = __builtin_amdgcn_mfma_f32_16x16x32_bf16(vf1.v, pf.v, ot[1][g], 0, 0, 0);
      }
    } else {
      ppk[0][0] = cpk[0][0]; ppk[0][1] = cpk[0][1];
      ppk[1][0] = cpk[1][0]; ppk[1][1] = cpk[1][1];
    }
  }

  barrier_lds();   // barrier #2: WAR vt -> opv (all waves done reading vt)

  // ---- Phase 3: normalize O_pv into opv (same-wave cross-lane only) ----
  float iv[2] = {1.f / lsum[0], 1.f / lsum[1]};
  #pragma unroll
  for (int ct = 0; ct < 2; ++ct)
    #pragma unroll
    for (int g = 0; g < 2; ++g) {
      int i = (2 * W + g) * 16 + li;
      #pragma unroll
      for (int reg = 0; reg < 4; ++reg)
        opv[(ct * 16 + quad * 4 + reg) * 129 + i] = f2b(ot[ct][g][reg] * iv[g]);
    }

  // ---- Phase 4: x_embed = Aacc x VE per own strip (per-wave aacc) ----
  #pragma unroll
  for (int g = 0; g < 2; ++g) {
    int ss = 2 * W + g;
    int t0 = (15 * ss) >> 4;
    int kb0 = (t0 & ~1) * 16;     // 32-aligned window base
    CFENCE();   // WAR: previous g's af reads vs zero-init below
    #pragma unroll
    for (int k = 0; k < 6; ++k) {
      int idx = k * 64 + t64;
      if (idx < 336) ((u32x4a*)wreg)[idx] = (u32x4){0, 0, 0, 0};
    }
    CFENCE();   // order zero-init (u32x4) before pp scatter (u16)
    int pbase = (ss + 7) * 15 + (li >> 1) + 7;
    #pragma unroll
    for (int js = 0; js < 8; ++js) {
      int p0 = pbase - 15 * js - 2 * quad;
      wreg[li * 168 + (p0 - kb0)] = (u16)pp[g][js];
      wreg[li * 168 + (p0 - 1 - kb0)] = (u16)(pp[g][js] >> 16);
    }
    CFENCE();   // RAW: pp scatter (u16) vs af reads (u32x4)
    f32x4 xa0 = zf, xa1 = zf;
    #pragma unroll
    for (int kt = 0; kt < 5; ++kt) {
      FU8 af, bf0, bf1;
      af.q = *(const u32x4a*)&wreg[li * 168 + kt * 32 + quad * 8];
      bf0.q = *(const u32x4*)(tabs + 61440 + h * 8192 + li * 256 + kb0 + kt * 32 + quad * 8);
      bf1.q = *(const u32x4*)(tabs + 61440 + h * 8192 + (16 + li) * 256 + kb0 + kt * 32 + quad * 8);
      xa0 = __builtin_amdgcn_mfma_f32_16x16x32_bf16(af.v, bf0.v, xa0, 0, 0, 0);
      xa1 = __builtin_amdgcn_mfma_f32_16x16x32_bf16(af.v, bf1.v, xa1, 0, 0, 0);
    }
    #pragma unroll
    for (int reg = 0; reg < 4; ++reg) {
      int irow = ss * 16 + quad * 4 + reg;
      float ivr = __shfl(iv[g], quad * 4 + reg, 64);
      int y = (wi * 8 + (irow >> 4) + 4) & 127;
      int x = (wj * 8 + ((irow >> 1) & 7) + 4) & 127;
      int ob = (((b * 128 + y) * 128 + x) * 2 + (irow & 1)) * 128 + h * 32;
      out[ob + li] = b2f(opv[li * 129 + irow]) + xa0[reg] * ivr;
      out[ob + 16 + li] = b2f(opv[(16 + li) * 129 + irow]) + xa1[reg] * ivr;
    }
  }
}

extern "C" void kernel_launch(void* const* d_in, const int* in_sizes, int n_in,
                              void* d_out, int out_size, void* d_ws, size_t ws_size,
                              hipStream_t stream) {
  const float* qkv = (const float*)d_in[0];
  // d_in[1] (attn_mask) and d_in[3] (rel_pos_index) unused: computed analytically.
  const float* rpe = (const float*)d_in[2];
  u16* tabs = (u16*)d_ws;  // 94208 u16 = 188,416 B

  prep_tabs<<<368, 256, 0, stream>>>(rpe, tabs);
  swin_mfma<<<4096, 256, 0, stream>>>(qkv, tabs, (float*)d_out);
}

// Round 6
// 431.940 us; speedup vs baseline: 1.0614x; 1.0614x over previous
//
#include <hip/hip_runtime.h>

typedef unsigned int u32;
typedef unsigned short u16;
typedef float f32x4 __attribute__((ext_vector_type(4)));
typedef short s16x8 __attribute__((ext_vector_type(8)));
typedef u32 __attribute__((ext_vector_type(4))) u32x4;

// may_alias views for LDS: the pool is accessed as u16 / u32 / u32x4 in
// different phases.
typedef u16 __attribute__((may_alias)) u16a;
typedef u32 __attribute__((may_alias)) u32a;
typedef u32x4 __attribute__((may_alias)) u32x4a;

// Compile-time-only fence: orders LDS stores vs dependent reads in the
// scheduler without emitting any instruction.
#define CFENCE() asm volatile("" ::: "memory")

constexpr float SCALE = 0.17677669529663687f;  // 32^-0.5

__device__ __forceinline__ u16 f2b(float f) {
  u32 x = __float_as_uint(f);
  return (u16)((x + 0x7fffu + ((x >> 16) & 1u)) >> 16);  // RNE-ish
}
__device__ __forceinline__ float b2f(u16 s) { return __uint_as_float(((u32)s) << 16); }
__device__ __forceinline__ u32 pk2(float lo, float hi) {
  return (u32)f2b(lo) | ((u32)f2b(hi) << 16);
}

union FU8 { s16x8 v; u32 u[4]; u32x4 q; };

// Barrier WITHOUT the vmcnt(0) drain __syncthreads() would emit.
__device__ __forceinline__ void barrier_lds() {
  asm volatile("s_waitcnt lgkmcnt(0)" ::: "memory");
  __builtin_amdgcn_s_barrier();
}

// ws tables (u16 bf16):
//   TK  [h][240][32] at 0      (k_embed, rows>=225 zero)      for QE = Q x TK^T
//   TQ  [h][240][32] at 30720  (q_embed*SCALE)                for KR = K x TQ^T
//   TVt [h][32][256] at 61440  (v_embed^T, pp>=225 zero)      for Aacc x VE
__global__ __launch_bounds__(256) void prep_tabs(const float* __restrict__ rpe,
                                                 u16* __restrict__ tabs) {
  int id = blockIdx.x * 256 + threadIdx.x;
  if (id >= 94208) return;
  float val = 0.f;
  if (id < 61440) {
    int tbl = id / 30720;          // 0 = TK, 1 = TQ
    int r   = id % 30720;
    int h   = r / 7680;
    int rr  = r % 7680;
    int row = rr / 32, c = rr % 32;
    if (row < 225) {
      val = rpe[row * 384 + h * 96 + (tbl == 0 ? 32 : 0) + c];
      if (tbl == 1) val *= SCALE;
    }
  } else {
    int id2 = id - 61440;
    int h  = id2 / 8192;
    int r2 = id2 % 8192;
    int pp = r2 % 256;
    int c  = r2 / 256;
    if (pp < 225) val = rpe[pp * 384 + h * 96 + 64 + c];
  }
  tabs[id] = f2b(val);
}

// 4 waves per (window, head); wave W owns i-strips {2W, 2W+1}.
// qe and pair-sums live in REGISTERS; KRT is per-wave private (each wave's
// i-strip needs only a 30-wide p-window = 3 TQ tiles), so the flash loop has
// ZERO barriers. Only 2 barriers total.
// __launch_bounds__(256, 2): round-5's (256,4) capped the allocator at 128
// VGPRs and it spilled down to 64 (WRITE_SIZE 184 MB vs 65 MB output =
// ~120 MB scratch writes/dispatch). Live pressure is ~110-130; min-waves=2
// gives a 256-VGPR budget -> no spills, 4 waves/SIMD natural.
// LDS pool 15104 u16 = 30208 B -> 5 blocks/CU by LDS:
//   vt   [32][136]            @0                 P0->P2 (V^T, u32-packed)
//   wreg per-wave 2688 u16    @4352 + W*2688 :
//        P1: scWT [144][18]   (QE strip, transposed [p][row])
//        P2: kbufT [48][18]   (KRT window, transposed)
//        P4: aacc [16][168]
//   opv  [32][129]            @0                 P3+ (over dead vt)
__global__ __launch_bounds__(256, 2) void swin_mfma(
    const float* __restrict__ qkv,   // [4,128,128,2,384]
    const u16*   __restrict__ tabs,
    float* __restrict__ out) {       // [4,128,128,2,128]
  __shared__ __align__(16) u16 pool[15104];
  u16a* const vt  = (u16a*)pool;
  u32a* const vt32 = (u32a*)pool;

  const int t = threadIdx.x;
  const int W = t >> 6;
  const int t64 = t & 63;
  const int li = t64 & 15, quad = t64 >> 4;
  u16a* const wreg = (u16a*)(pool + 4352 + W * 2688);
  u32a* const wreg32 = (u32a*)wreg;
  u16a* const opv = (u16a*)pool;

  int blk = blockIdx.x;
  blk = ((blk & 7) << 9) | (blk >> 3);   // XCD-aware swizzle (4096 % 8 == 0)
  const int h = blk & 3;
  const int w = blk >> 2;
  const int b = w >> 8;
  const int nw = w & 255;
  const int wi = nw >> 4, wj = nw & 15;
  const bool wi15 = (wi == 15), wj15 = (wj == 15);

  auto tokoff = [&](int m) -> int {
    int y = (wi * 8 + (m >> 4) + 4) & 127;
    int x = (wj * 8 + ((m >> 1) & 7) + 4) & 127;
    return (((b * 128 + y) * 128 + x) * 2 + (m & 1)) * 384;
  };

  // ---- Phase 0a: V^T staging — pair p = t64 (0..63), 8 channels per wave ----
  {
    int p = t64;
    int ch0 = W * 8;
    int vb = tokoff(2 * p) + 256 + h * 32 + ch0;
    float4 a0 = *(const float4*)(qkv + vb);
    float4 a1 = *(const float4*)(qkv + vb + 4);
    float4 c0 = *(const float4*)(qkv + vb + 384);   // same pixel, n=1
    float4 c1 = *(const float4*)(qkv + vb + 388);
    vt32[(ch0 + 0) * 68 + p] = pk2(a0.x, c0.x);
    vt32[(ch0 + 1) * 68 + p] = pk2(a0.y, c0.y);
    vt32[(ch0 + 2) * 68 + p] = pk2(a0.z, c0.z);
    vt32[(ch0 + 3) * 68 + p] = pk2(a0.w, c0.w);
    vt32[(ch0 + 4) * 68 + p] = pk2(a1.x, c1.x);
    vt32[(ch0 + 5) * 68 + p] = pk2(a1.y, c1.y);
    vt32[(ch0 + 6) * 68 + p] = pk2(a1.z, c1.z);
    vt32[(ch0 + 7) * 68 + p] = pk2(a1.w, c1.w);
  }

  // ---- Phase 0b: Q (scaled by SCALE) and all K fragments ----
  const float QS = SCALE;
  FU8 qf[2];
  #pragma unroll
  for (int g = 0; g < 2; ++g) {
    int base = tokoff((2 * W + g) * 16 + li) + h * 32 + quad * 8;
    float4 a = *(const float4*)(qkv + base);
    float4 c = *(const float4*)(qkv + base + 4);
    qf[g].u[0] = pk2(a.x * QS, a.y * QS);
    qf[g].u[1] = pk2(a.z * QS, a.w * QS);
    qf[g].u[2] = pk2(c.x * QS, c.y * QS);
    qf[g].u[3] = pk2(c.z * QS, c.w * QS);
  }
  FU8 kf[8];
  #pragma unroll
  for (int js = 0; js < 8; ++js) {
    int kb = tokoff(js * 16 + li) + 128 + h * 32 + quad * 8;
    float4 a = *(const float4*)(qkv + kb);
    float4 c = *(const float4*)(qkv + kb + 4);
    kf[js].u[0] = pk2(a.x, a.y); kf[js].u[1] = pk2(a.z, a.w);
    kf[js].u[2] = pk2(c.x, c.y); kf[js].u[3] = pk2(c.z, c.w);
  }

  const f32x4 zf = {0.f, 0.f, 0.f, 0.f};

  // ---- Phase 1: QE strips into scWT (per-wave), gather into REGISTERS ----
  u32 qe[2][8];
  #pragma unroll
  for (int g = 0; g < 2; ++g) {
    int ss = 2 * W + g;
    int t0 = (15 * ss) >> 4;
    CFENCE();   // WAR: previous g's gather reads vs this g's stores
    #pragma unroll
    for (int tt = 0; tt < 9; ++tt) {
      FU8 bf;
      bf.q = *(const u32x4*)(tabs + h * 7680 + ((t0 + tt) * 16 + li) * 32 + quad * 8);
      f32x4 acc = __builtin_amdgcn_mfma_f32_16x16x32_bf16(qf[g].v, bf.v, zf, 0, 0, 0);
      u32 idx = (u32)((tt * 16 + li) * 9 + 2 * quad);   // [p][row] u32 pairs
      wreg32[idx] = pk2(acc[0], acc[1]);
      wreg32[idx + 1] = pk2(acc[2], acc[3]);
    }
    CFENCE();   // RAW: stores above vs u16 gather reads below
    int pbase = (ss + 7) * 15 + (li >> 1) + 7;
    int co = t0 * 16;
    #pragma unroll
    for (int js = 0; js < 8; ++js) {
      int p0 = pbase - 15 * js - 2 * quad;
      u32 lo = wreg[(p0 - co) * 18 + li];
      u32 hi = wreg[(p0 - 1 - co) * 18 + li];
      qe[g][js] = lo | (hi << 16);
    }
  }

  barrier_lds();   // barrier #1: vt visible to all (first cross-wave read: PV js=1)

  // ---- Phase 2: flash over j-strips — NO barriers ----
  f32x4 ot[2][2] = {{zf, zf}, {zf, zf}};
  float lsum[2] = {0.f, 0.f};
  u32 pp[2][8];
  u32 ppk[2][2] = {{0, 0}, {0, 0}};
  const int rx_i = wj15 ? (((li >> 1) < 4) ? 1 : 2) : 0;

  #pragma unroll
  for (int js = 0; js < 8; ++js) {
    // per-wave KRT: 3 tiles covering this wave's 30-wide p-window
    const int pw0 = 15 * (2 * W + 7 - js);
    const int pt0 = pw0 >> 4;
    const int cok = pt0 * 16;
    CFENCE();   // WAR: previous js's kbuf reads vs this js's stores
    #pragma unroll
    for (int k = 0; k < 3; ++k) {
      FU8 bf;
      bf.q = *(const u32x4*)(tabs + 30720 + h * 7680 + ((pt0 + k) * 16 + li) * 32 + quad * 8);
      f32x4 acc = __builtin_amdgcn_mfma_f32_16x16x32_bf16(kf[js].v, bf.v, zf, 0, 0, 0);
      u32 idx = (u32)((k * 16 + li) * 9 + 2 * quad);    // kbufT [p][row]
      wreg32[idx] = pk2(acc[0], acc[1]);
      wreg32[idx + 1] = pk2(acc[2], acc[3]);
    }
    CFENCE();   // RAW: kbuf stores vs u16 reads in the g-loop

    const int ry_j = wi15 ? ((js < 4) ? 1 : 2) : 0;
    u32 cpk[2][2];
    #pragma unroll
    for (int g = 0; g < 2; ++g) {
      const int it = 2 * W + g;
      f32x4 s = __builtin_amdgcn_mfma_f32_16x16x32_bf16(kf[js].v, qf[g].v, zf, 0, 0, 0);
      const int ry_i = wi15 ? ((it < 4) ? 1 : 2) : 0;
      const int pbq = (it + 7) * 15 + (li >> 1) + 7 - 15 * js;
      const float qeL = b2f((u16)qe[g][js]);
      const float qeH = b2f((u16)(qe[g][js] >> 16));
      float e[4];
      #pragma unroll
      for (int reg = 0; reg < 4; ++reg) {
        int jl = quad * 4 + reg;
        int jw = jl >> 1;
        int rx_j = wj15 ? ((jw < 4) ? 1 : 2) : 0;
        float v = s[reg] + b2f(wreg[(pbq - jw - cok) * 18 + jl]) +
                  ((reg < 2) ? qeL : qeH);
        bool open = (ry_i == ry_j) && (rx_i == rx_j) &&
                    !((it == js) && ((li >> 1) == jw) && (li != jl));
        e[reg] = open ? __expf(v) : 0.f;
      }
      float a01 = e[0] + e[1], a23 = e[2] + e[3];
      float cs = a01 + a23;
      cs += __shfl_xor(cs, 16, 64);
      cs += __shfl_xor(cs, 32, 64);
      lsum[g] += cs;
      pp[g][js] = pk2(a01, a23);          // pair-sums, kept in registers
      cpk[g][0] = pk2(e[0], e[1]);
      cpk[g][1] = pk2(e[2], e[3]);
    }

    if (js & 1) {  // PV for the completed 32-j block: P via shuffles
      const int pairbase = (js >> 1) * 32;
      FU8 vf0, vf1;
      vf0.q = *(const u32x4a*)&vt[li * 136 + pairbase + quad * 8];
      vf1.q = *(const u32x4a*)&vt[(16 + li) * 136 + pairbase + quad * 8];
      #pragma unroll
      for (int g = 0; g < 2; ++g) {
        FU8 pf;   // B-frag: k = quad*8+e -> src quad (2*(quad&1)+(w>>1)), word (w&1)
        #pragma unroll
        for (int w2 = 0; w2 < 4; ++w2) {
          int srcLane = (2 * (quad & 1) + (w2 >> 1)) * 16 + li;
          u32 rp = (u32)__shfl((int)ppk[g][w2 & 1], srcLane, 64);
          u32 rc = (u32)__shfl((int)cpk[g][w2 & 1], srcLane, 64);
          pf.u[w2] = (quad < 2) ? rp : rc;
        }
        ot[0][g] = __builtin_amdgcn_mfma_f32_16x16x32_bf16(vf0.v, pf.v, ot[0][g], 0, 0, 0);
        ot[1][g] = __builtin_amdgcn_mfma_f32_16x16x32_bf16(vf1.v, pf.v, ot[1][g], 0, 0, 0);
      }
    } else {
      ppk[0][0] = cpk[0][0]; ppk[0][1] = cpk[0][1];
      ppk[1][0] = cpk[1][0]; ppk[1][1] = cpk[1][1];
    }
  }

  barrier_lds();   // barrier #2: WAR vt -> opv (all waves done reading vt)

  // ---- Phase 3: normalize O_pv into opv (same-wave cross-lane only) ----
  float iv[2] = {1.f / lsum[0], 1.f / lsum[1]};
  #pragma unroll
  for (int ct = 0; ct < 2; ++ct)
    #pragma unroll
    for (int g = 0; g < 2; ++g) {
      int i = (2 * W + g) * 16 + li;
      #pragma unroll
      for (int reg = 0; reg < 4; ++reg)
        opv[(ct * 16 + quad * 4 + reg) * 129 + i] = f2b(ot[ct][g][reg] * iv[g]);
    }

  // ---- Phase 4: x_embed = Aacc x VE per own strip (per-wave aacc) ----
  #pragma unroll
  for (int g = 0; g < 2; ++g) {
    int ss = 2 * W + g;
    int t0 = (15 * ss) >> 4;
    int kb0 = (t0 & ~1) * 16;     // 32-aligned window base
    CFENCE();   // WAR: previous g's af reads vs zero-init below
    #pragma unroll
    for (int k = 0; k < 6; ++k) {
      int idx = k * 64 + t64;
      if (idx < 336) ((u32x4a*)wreg)[idx] = (u32x4){0, 0, 0, 0};
    }
    CFENCE();   // order zero-init (u32x4) before pp scatter (u16)
    int pbase = (ss + 7) * 15 + (li >> 1) + 7;
    #pragma unroll
    for (int js = 0; js < 8; ++js) {
      int p0 = pbase - 15 * js - 2 * quad;
      wreg[li * 168 + (p0 - kb0)] = (u16)pp[g][js];
      wreg[li * 168 + (p0 - 1 - kb0)] = (u16)(pp[g][js] >> 16);
    }
    CFENCE();   // RAW: pp scatter (u16) vs af reads (u32x4)
    f32x4 xa0 = zf, xa1 = zf;
    #pragma unroll
    for (int kt = 0; kt < 5; ++kt) {
      FU8 af, bf0, bf1;
      af.q = *(const u32x4a*)&wreg[li * 168 + kt * 32 + quad * 8];
      bf0.q = *(const u32x4*)(tabs + 61440 + h * 8192 + li * 256 + kb0 + kt * 32 + quad * 8);
      bf1.q = *(const u32x4*)(tabs + 61440 + h * 8192 + (16 + li) * 256 + kb0 + kt * 32 + quad * 8);
      xa0 = __builtin_amdgcn_mfma_f32_16x16x32_bf16(af.v, bf0.v, xa0, 0, 0, 0);
      xa1 = __builtin_amdgcn_mfma_f32_16x16x32_bf16(af.v, bf1.v, xa1, 0, 0, 0);
    }
    #pragma unroll
    for (int reg = 0; reg < 4; ++reg) {
      int irow = ss * 16 + quad * 4 + reg;
      float ivr = __shfl(iv[g], quad * 4 + reg, 64);
      int y = (wi * 8 + (irow >> 4) + 4) & 127;
      int x = (wj * 8 + ((irow >> 1) & 7) + 4) & 127;
      int ob = (((b * 128 + y) * 128 + x) * 2 + (irow & 1)) * 128 + h * 32;
      out[ob + li] = b2f(opv[li * 129 + irow]) + xa0[reg] * ivr;
      out[ob + 16 + li] = b2f(opv[(16 + li) * 129 + irow]) + xa1[reg] * ivr;
    }
  }
}

extern "C" void kernel_launch(void* const* d_in, const int* in_sizes, int n_in,
                              void* d_out, int out_size, void* d_ws, size_t ws_size,
                              hipStream_t stream) {
  const float* qkv = (const float*)d_in[0];
  // d_in[1] (attn_mask) and d_in[3] (rel_pos_index) unused: computed analytically.
  const float* rpe = (const float*)d_in[2];
  u16* tabs = (u16*)d_ws;  // 94208 u16 = 188,416 B

  prep_tabs<<<368, 256, 0, stream>>>(rpe, tabs);
  swin_mfma<<<4096, 256, 0, stream>>>(qkv, tabs, (float*)d_out);
}